// Round 1
// baseline (189.958 us; speedup 1.0000x reference)
//
#include <hip/hip_runtime.h>
#include <math.h>

__device__ __forceinline__ float silu_act(float y) {
    return y / (1.f + __expf(-y));
}

// Pointwise 1x1 conv + scale/bias + SiLU.
// in: [B, Cin, HW], w: [Cout, Cin], out written at channel offset 0 of a buffer
// with channel stride CoutStride. Each thread: one pixel, TC output channels.
template<int TC>
__global__ void pw_conv_silu(const float* __restrict__ in, int Cin, int HW, int B,
                             const float* __restrict__ w,
                             const float* __restrict__ sc, const float* __restrict__ bi,
                             float* __restrict__ out, int CoutStride) {
    int g = blockIdx.x * blockDim.x + threadIdx.x;
    if (g >= B * HW) return;
    int b = g / HW, pix = g - b * HW;
    int co0 = blockIdx.y * TC;
    float acc[TC];
#pragma unroll
    for (int j = 0; j < TC; ++j) acc[j] = 0.f;
    const float* ip = in + (size_t)b * Cin * HW + pix;
    const float* wp = w + (size_t)co0 * Cin;
    for (int ci = 0; ci < Cin; ++ci) {
        float v = ip[(size_t)ci * HW];
#pragma unroll
        for (int j = 0; j < TC; ++j)
            acc[j] = fmaf(v, wp[j * Cin + ci], acc[j]);
    }
#pragma unroll
    for (int j = 0; j < TC; ++j) {
        int co = co0 + j;
        float y = fmaf(acc[j], sc[co], bi[co]);
        out[((size_t)b * CoutStride + co) * HW + pix] = silu_act(y);
    }
}

// Fused depthwise 3x3 (channels [0,ch)) and 5x5 (channels [ch,2ch)) + SiLU.
// Reads cat channels [0, 2ch), writes cat channels [2ch, 4ch).
__global__ void dw_conv_silu(float* __restrict__ cat, int ch, int H, int W, int Ctot, int B,
                             const float* __restrict__ w3, const float* __restrict__ s3,
                             const float* __restrict__ b3,
                             const float* __restrict__ w5, const float* __restrict__ s5,
                             const float* __restrict__ b5) {
    int HW = H * W;
    int idx = blockIdx.x * blockDim.x + threadIdx.x;
    int total = B * 2 * ch * HW;
    if (idx >= total) return;
    int pix = idx % HW;
    int t = idx / HW;
    int c2 = t % (2 * ch);
    int b = t / (2 * ch);
    int x = pix % W, y = pix / W;
    const float* ip = cat + ((size_t)b * Ctot + c2) * HW;
    float acc = 0.f, scale, bias;
    if (c2 < ch) {
        const float* wk = w3 + c2 * 9;
#pragma unroll
        for (int ky = 0; ky < 3; ++ky) {
            int iy = y + ky - 1;
            if ((unsigned)iy >= (unsigned)H) continue;
#pragma unroll
            for (int kx = 0; kx < 3; ++kx) {
                int ix = x + kx - 1;
                if ((unsigned)ix >= (unsigned)W) continue;
                acc = fmaf(ip[iy * W + ix], wk[ky * 3 + kx], acc);
            }
        }
        scale = s3[c2]; bias = b3[c2];
    } else {
        int c = c2 - ch;
        const float* wk = w5 + c * 25;
#pragma unroll
        for (int ky = 0; ky < 5; ++ky) {
            int iy = y + ky - 2;
            if ((unsigned)iy >= (unsigned)H) continue;
#pragma unroll
            for (int kx = 0; kx < 5; ++kx) {
                int ix = x + kx - 2;
                if ((unsigned)ix >= (unsigned)W) continue;
                acc = fmaf(ip[iy * W + ix], wk[ky * 5 + kx], acc);
            }
        }
        scale = s5[c]; bias = b5[c];
    }
    float v = fmaf(acc, scale, bias);
    cat[((size_t)b * Ctot + 2 * ch + c2) * HW + pix] = silu_act(v);
}

// CARAFE: pixel-shuffle + softmax(25) + 5x5 dilated reassembly of nearest-up(2) X.
// X: [B,128,64,64], Wenc: [B,100,64,64], out: [B,128,128,128].
// Block = (oy row, channel half, batch); weights for the 128 ox positions of
// this row are softmaxed once in LDS and reused by all channels.
__global__ void carafe_kernel(const float* __restrict__ X, const float* __restrict__ Wenc,
                              float* __restrict__ out) {
    const int H = 64, Wd = 64, C = 128, Ho = 128, Wo = 128;
    int oy = blockIdx.x;          // 0..127
    int chalf = blockIdx.y;       // 0..1 (channels 0-63 / 64-127)
    int b = blockIdx.z;
    __shared__ float sw[25][128];
    int t = threadIdx.x;          // 256 threads
    int ry2 = (oy & 1) * 2, Y = oy >> 1;
    const float* wb = Wenc + (size_t)b * 100 * H * Wd + (size_t)Y * Wd;
    // load raw pixel-shuffled weights: W_ps[j][ox] = Wraw[b, j*4+ry*2+rx, Y, ox/2]
    for (int i = t; i < 25 * 128; i += 256) {
        int j = i >> 7;
        int ox = i & 127;
        int chW = j * 4 + ry2 + (ox & 1);
        sw[j][ox] = wb[(size_t)chW * H * Wd + (ox >> 1)];
    }
    __syncthreads();
    // softmax over the 25 taps, one thread per ox
    if (t < 128) {
        float m = -1e30f;
#pragma unroll
        for (int j = 0; j < 25; ++j) m = fmaxf(m, sw[j][t]);
        float e[25];
        float s = 0.f;
#pragma unroll
        for (int j = 0; j < 25; ++j) { e[j] = __expf(sw[j][t] - m); s += e[j]; }
        float inv = 1.f / s;
#pragma unroll
        for (int j = 0; j < 25; ++j) sw[j][t] = e[j] * inv;
    }
    __syncthreads();
    int ox = t & 127;
    int cpar = t >> 7;            // 0..1
    float wreg[25];
#pragma unroll
    for (int j = 0; j < 25; ++j) wreg[j] = sw[j][ox];
    int Xc = ox >> 1;
    const float* Xb = X + (size_t)b * C * H * Wd;
    int c0 = chalf * 64 + cpar;
    int cend = chalf * 64 + 64;
    for (int c = c0; c < cend; c += 2) {
        const float* xc = Xb + (size_t)c * H * Wd;
        float acc = 0.f;
#pragma unroll
        for (int p = 0; p < 5; ++p) {
            int iy = Y + p - 2;
            if ((unsigned)iy >= (unsigned)H) continue;
            const float* row = xc + iy * Wd;
#pragma unroll
            for (int q = 0; q < 5; ++q) {
                int ix = Xc + q - 2;
                float v = ((unsigned)ix < (unsigned)Wd) ? row[ix] : 0.f;
                acc = fmaf(wreg[p * 5 + q], v, acc);
            }
        }
        out[(((size_t)b * C + c) * Ho + oy) * Wo + ox] = acc;
    }
}

extern "C" void kernel_launch(void* const* d_in, const int* in_sizes, int n_in,
                              void* d_out, int out_size, void* d_ws, size_t ws_size,
                              hipStream_t stream) {
    const float* X          = (const float*)d_in[0];
    const float* comp_cv1_w = (const float*)d_in[1];
    const float* comp_cv1_s = (const float*)d_in[2];
    const float* comp_cv1_b = (const float*)d_in[3];
    const float* comp_dw3_w = (const float*)d_in[4];
    const float* comp_dw3_s = (const float*)d_in[5];
    const float* comp_dw3_b = (const float*)d_in[6];
    const float* comp_dw5_w = (const float*)d_in[7];
    const float* comp_dw5_s = (const float*)d_in[8];
    const float* comp_dw5_b = (const float*)d_in[9];
    const float* comp_px_w  = (const float*)d_in[10];
    const float* comp_px_s  = (const float*)d_in[11];
    const float* comp_px_b  = (const float*)d_in[12];
    const float* enc_cv1_w  = (const float*)d_in[13];
    const float* enc_cv1_s  = (const float*)d_in[14];
    const float* enc_cv1_b  = (const float*)d_in[15];
    const float* enc_dw3_w  = (const float*)d_in[16];
    const float* enc_dw3_s  = (const float*)d_in[17];
    const float* enc_dw3_b  = (const float*)d_in[18];
    const float* enc_dw5_w  = (const float*)d_in[19];
    const float* enc_dw5_s  = (const float*)d_in[20];
    const float* enc_dw5_b  = (const float*)d_in[21];
    const float* enc_px_w   = (const float*)d_in[22];
    const float* enc_px_s   = (const float*)d_in[23];
    const float* enc_px_b   = (const float*)d_in[24];
    float* out = (float*)d_out;

    const int B = 2, H = 64, W = 64, HW = H * W;
    // workspace layout (floats)
    float* cat_c  = (float*)d_ws;                      // [B, 64, HW]  (x1:0-31, x2:32-63)
    float* y_comp = cat_c  + (size_t)B * 64 * HW;      // [B, 64, HW]
    float* cat_e  = y_comp + (size_t)B * 64 * HW;      // [B,100, HW]  (x1:0-49, x2:50-99)
    float* wraw   = cat_e  + (size_t)B * 100 * HW;     // [B,100, HW]

    int pixBlocks = (B * HW + 255) / 256;   // 32

    // comp MSGConv
    pw_conv_silu<8><<<dim3(pixBlocks, 4), 256, 0, stream>>>(
        X, 128, HW, B, comp_cv1_w, comp_cv1_s, comp_cv1_b, cat_c, 64);
    {
        int n = B * 32 * HW;
        dw_conv_silu<<<(n + 255) / 256, 256, 0, stream>>>(
            cat_c, 16, H, W, 64, B,
            comp_dw3_w, comp_dw3_s, comp_dw3_b,
            comp_dw5_w, comp_dw5_s, comp_dw5_b);
    }
    pw_conv_silu<8><<<dim3(pixBlocks, 8), 256, 0, stream>>>(
        cat_c, 64, HW, B, comp_px_w, comp_px_s, comp_px_b, y_comp, 64);

    // enc MSGConv
    pw_conv_silu<10><<<dim3(pixBlocks, 5), 256, 0, stream>>>(
        y_comp, 64, HW, B, enc_cv1_w, enc_cv1_s, enc_cv1_b, cat_e, 100);
    {
        int n = B * 50 * HW;
        dw_conv_silu<<<(n + 255) / 256, 256, 0, stream>>>(
            cat_e, 25, H, W, 100, B,
            enc_dw3_w, enc_dw3_s, enc_dw3_b,
            enc_dw5_w, enc_dw5_s, enc_dw5_b);
    }
    pw_conv_silu<10><<<dim3(pixBlocks, 10), 256, 0, stream>>>(
        cat_e, 100, HW, B, enc_px_w, enc_px_s, enc_px_b, wraw, 100);

    // CARAFE reassembly
    carafe_kernel<<<dim3(128, 2, B), 256, 0, stream>>>(X, wraw, out);
}

// Round 2
// 90.303 us; speedup vs baseline: 2.1036x; 2.1036x over previous
//
#include <hip/hip_runtime.h>
#include <math.h>

__device__ __forceinline__ float silu_act(float y) {
    return y / (1.f + __expf(-y));
}

// Pointwise 1x1 conv + scale/bias + SiLU. Compile-time Cin for full unroll.
// in: [B, Cin, HW], w: [Cout, Cin]; out at channel offset 0, stride CoutStride.
template<int TC, int CIN>
__global__ void pw_conv_silu(const float* __restrict__ in, int HW, int B,
                             const float* __restrict__ w,
                             const float* __restrict__ sc, const float* __restrict__ bi,
                             float* __restrict__ out, int CoutStride) {
    int g = blockIdx.x * blockDim.x + threadIdx.x;
    if (g >= B * HW) return;
    int b = g / HW, pix = g - b * HW;
    int co0 = blockIdx.y * TC;
    float acc[TC];
#pragma unroll
    for (int j = 0; j < TC; ++j) acc[j] = 0.f;
    const float* ip = in + (size_t)b * CIN * HW + pix;
    const float* wp = w + (size_t)co0 * CIN;
#pragma unroll 8
    for (int ci = 0; ci < CIN; ++ci) {
        float v = ip[(size_t)ci * HW];
#pragma unroll
        for (int j = 0; j < TC; ++j)
            acc[j] = fmaf(v, wp[j * CIN + ci], acc[j]);
    }
#pragma unroll
    for (int j = 0; j < TC; ++j) {
        int co = co0 + j;
        float y = fmaf(acc[j], sc[co], bi[co]);
        out[((size_t)b * CoutStride + co) * HW + pix] = silu_act(y);
    }
}

// Fused depthwise 3x3 (channels [0,ch)) and 5x5 (channels [ch,2ch)) + SiLU.
// Reads cat channels [0, 2ch), writes cat channels [2ch, 4ch).
__global__ void dw_conv_silu(float* __restrict__ cat, int ch, int H, int W, int Ctot, int B,
                             const float* __restrict__ w3, const float* __restrict__ s3,
                             const float* __restrict__ b3,
                             const float* __restrict__ w5, const float* __restrict__ s5,
                             const float* __restrict__ b5) {
    int HW = H * W;
    int idx = blockIdx.x * blockDim.x + threadIdx.x;
    int total = B * 2 * ch * HW;
    if (idx >= total) return;
    int pix = idx % HW;
    int t = idx / HW;
    int c2 = t % (2 * ch);
    int b = t / (2 * ch);
    int x = pix % W, y = pix / W;
    const float* ip = cat + ((size_t)b * Ctot + c2) * HW;
    float acc = 0.f, scale, bias;
    if (c2 < ch) {
        const float* wk = w3 + c2 * 9;
#pragma unroll
        for (int ky = 0; ky < 3; ++ky) {
            int iy = y + ky - 1;
            if ((unsigned)iy >= (unsigned)H) continue;
#pragma unroll
            for (int kx = 0; kx < 3; ++kx) {
                int ix = x + kx - 1;
                if ((unsigned)ix >= (unsigned)W) continue;
                acc = fmaf(ip[iy * W + ix], wk[ky * 3 + kx], acc);
            }
        }
        scale = s3[c2]; bias = b3[c2];
    } else {
        int c = c2 - ch;
        const float* wk = w5 + c * 25;
#pragma unroll
        for (int ky = 0; ky < 5; ++ky) {
            int iy = y + ky - 2;
            if ((unsigned)iy >= (unsigned)H) continue;
#pragma unroll
            for (int kx = 0; kx < 5; ++kx) {
                int ix = x + kx - 2;
                if ((unsigned)ix >= (unsigned)W) continue;
                acc = fmaf(ip[iy * W + ix], wk[ky * 5 + kx], acc);
            }
        }
        scale = s5[c]; bias = b5[c];
    }
    float v = fmaf(acc, scale, bias);
    cat[((size_t)b * Ctot + 2 * ch + c2) * HW + pix] = silu_act(v);
}

// CARAFE v2: LDS-staged, 4-output register blocking.
// Block = (input row Y, 32-channel chunk, batch). Computes oy in {2Y, 2Y+1},
// all 128 ox, 32 channels. X rows Y-2..Y+2 for the chunk staged in LDS;
// softmaxed weights for both output rows kept in LDS pair-split:
// sw[r][j][par][l] where ox = 2*l + par.
__global__ void carafe_kernel(const float* __restrict__ X, const float* __restrict__ Wenc,
                              float* __restrict__ out) {
    const int H = 64, Wd = 64, C = 128, Ho = 128, Wo = 128, HW = H * Wd;
    int Y = blockIdx.x;           // 0..63
    int cchunk = blockIdx.y;      // 0..3
    int b = blockIdx.z;
    __shared__ float xs[32][5][64];        // 40 KB
    __shared__ float sw[2][25][2][64];     // 25.6 KB
    int t = threadIdx.x;          // 256 threads

    // ---- load raw pixel-shuffled weights for both output rows ----
    const float* wb = Wenc + (size_t)b * 100 * HW + (size_t)Y * Wd;
    for (int i = t; i < 2 * 25 * 128; i += 256) {
        int l = i & 63;
        int par = (i >> 6) & 1;
        int j = (i >> 7) % 25;
        int r = i / (128 * 25);
        int chW = j * 4 + r * 2 + par;
        sw[r][j][par][l] = wb[(size_t)chW * HW + l];
    }
    // ---- stage X rows ----
    int c0 = cchunk * 32;
    const float* Xb = X + ((size_t)b * C + c0) * HW;
    for (int i = t; i < 32 * 5 * 64; i += 256) {
        int x = i & 63;
        int p = (i >> 6) % 5;
        int c = i / (64 * 5);
        int iy = Y + p - 2;
        xs[c][p][x] = ((unsigned)iy < (unsigned)H) ? Xb[(size_t)c * HW + iy * Wd + x] : 0.f;
    }
    __syncthreads();

    // ---- softmax over 25 taps: 256 threads cover 2 rows x 128 ox ----
    {
        int l = t & 63;
        int par = (t >> 6) & 1;
        int r = t >> 7;
        float m = -1e30f;
#pragma unroll
        for (int j = 0; j < 25; ++j) m = fmaxf(m, sw[r][j][par][l]);
        float e[25];
        float s = 0.f;
#pragma unroll
        for (int j = 0; j < 25; ++j) { e[j] = __expf(sw[r][j][par][l] - m); s += e[j]; }
        float inv = 1.f / s;
#pragma unroll
        for (int j = 0; j < 25; ++j) sw[r][j][par][l] = e[j] * inv;
    }
    __syncthreads();

    // ---- compute: thread = (ox-pair l, channel group tc) ----
    int l = t & 63;               // Xc = l, ox = 2l, 2l+1
    int tc = t >> 6;              // 0..3
    for (int k = 0; k < 8; ++k) {
        int c = tc * 8 + k;
        float xv[25];
#pragma unroll
        for (int p = 0; p < 5; ++p)
#pragma unroll
            for (int q = 0; q < 5; ++q) {
                int ix = l + q - 2;
                xv[p * 5 + q] = ((unsigned)ix < (unsigned)Wd) ? xs[c][p][ix] : 0.f;
            }
        float a00 = 0.f, a01 = 0.f, a10 = 0.f, a11 = 0.f;
#pragma unroll
        for (int j = 0; j < 25; ++j) {
            float v = xv[j];
            a00 = fmaf(sw[0][j][0][l], v, a00);
            a01 = fmaf(sw[0][j][1][l], v, a01);
            a10 = fmaf(sw[1][j][0][l], v, a10);
            a11 = fmaf(sw[1][j][1][l], v, a11);
        }
        size_t ob = (((size_t)b * C + (c0 + c)) * Ho + 2 * Y) * Wo;
        *reinterpret_cast<float2*>(&out[ob + 2 * l])      = make_float2(a00, a01);
        *reinterpret_cast<float2*>(&out[ob + Wo + 2 * l]) = make_float2(a10, a11);
    }
}

extern "C" void kernel_launch(void* const* d_in, const int* in_sizes, int n_in,
                              void* d_out, int out_size, void* d_ws, size_t ws_size,
                              hipStream_t stream) {
    const float* X          = (const float*)d_in[0];
    const float* comp_cv1_w = (const float*)d_in[1];
    const float* comp_cv1_s = (const float*)d_in[2];
    const float* comp_cv1_b = (const float*)d_in[3];
    const float* comp_dw3_w = (const float*)d_in[4];
    const float* comp_dw3_s = (const float*)d_in[5];
    const float* comp_dw3_b = (const float*)d_in[6];
    const float* comp_dw5_w = (const float*)d_in[7];
    const float* comp_dw5_s = (const float*)d_in[8];
    const float* comp_dw5_b = (const float*)d_in[9];
    const float* comp_px_w  = (const float*)d_in[10];
    const float* comp_px_s  = (const float*)d_in[11];
    const float* comp_px_b  = (const float*)d_in[12];
    const float* enc_cv1_w  = (const float*)d_in[13];
    const float* enc_cv1_s  = (const float*)d_in[14];
    const float* enc_cv1_b  = (const float*)d_in[15];
    const float* enc_dw3_w  = (const float*)d_in[16];
    const float* enc_dw3_s  = (const float*)d_in[17];
    const float* enc_dw3_b  = (const float*)d_in[18];
    const float* enc_dw5_w  = (const float*)d_in[19];
    const float* enc_dw5_s  = (const float*)d_in[20];
    const float* enc_dw5_b  = (const float*)d_in[21];
    const float* enc_px_w   = (const float*)d_in[22];
    const float* enc_px_s   = (const float*)d_in[23];
    const float* enc_px_b   = (const float*)d_in[24];
    float* out = (float*)d_out;

    const int B = 2, H = 64, W = 64, HW = H * W;
    float* cat_c  = (float*)d_ws;                      // [B, 64, HW]
    float* y_comp = cat_c  + (size_t)B * 64 * HW;      // [B, 64, HW]
    float* cat_e  = y_comp + (size_t)B * 64 * HW;      // [B,100, HW]
    float* wraw   = cat_e  + (size_t)B * 100 * HW;     // [B,100, HW]

    int pixBlocks = (B * HW + 255) / 256;   // 32

    // comp MSGConv
    pw_conv_silu<4, 128><<<dim3(pixBlocks, 8), 256, 0, stream>>>(
        X, HW, B, comp_cv1_w, comp_cv1_s, comp_cv1_b, cat_c, 64);
    {
        int n = B * 32 * HW;
        dw_conv_silu<<<(n + 255) / 256, 256, 0, stream>>>(
            cat_c, 16, H, W, 64, B,
            comp_dw3_w, comp_dw3_s, comp_dw3_b,
            comp_dw5_w, comp_dw5_s, comp_dw5_b);
    }
    pw_conv_silu<4, 64><<<dim3(pixBlocks, 16), 256, 0, stream>>>(
        cat_c, HW, B, comp_px_w, comp_px_s, comp_px_b, y_comp, 64);

    // enc MSGConv
    pw_conv_silu<5, 64><<<dim3(pixBlocks, 10), 256, 0, stream>>>(
        y_comp, HW, B, enc_cv1_w, enc_cv1_s, enc_cv1_b, cat_e, 100);
    {
        int n = B * 50 * HW;
        dw_conv_silu<<<(n + 255) / 256, 256, 0, stream>>>(
            cat_e, 25, H, W, 100, B,
            enc_dw3_w, enc_dw3_s, enc_dw3_b,
            enc_dw5_w, enc_dw5_s, enc_dw5_b);
    }
    pw_conv_silu<5, 100><<<dim3(pixBlocks, 20), 256, 0, stream>>>(
        cat_e, HW, B, enc_px_w, enc_px_s, enc_px_b, wraw, 100);

    // CARAFE reassembly
    carafe_kernel<<<dim3(64, 4, B), 256, 0, stream>>>(X, wraw, out);
}